// Round 9
// baseline (1781.105 us; speedup 1.0000x reference)
//
#include <hip/hip_runtime.h>
#include <math.h>

#define NFFT  512
#define WINL  320
#define HOP   160
#define FPAD  256
#define NF    257
#define TT    601
#define LSEQ  96000
#define XPLEN 96512
#define NCH   8
#define NB    8
#define NSEQ  64
#define NROWS 38464   // NSEQ*TT
#define DD    514
#define HH    128
#define G4    512
#define KPAD  544     // 17*32, zero-padded K for split-B arrays

typedef _Float16 h2v __attribute__((ext_vector_type(2)));
typedef short bf16x8 __attribute__((ext_vector_type(8)));
typedef float f32x4 __attribute__((ext_vector_type(4)));

// ---------------- init helpers ----------------
__device__ __forceinline__ float winval(int k) {
  if (k < 96 || k >= 416) return 0.f;
  return 0.5f - 0.5f * cosf((float)(2.0 * M_PI / 320.0) * (float)(k - 96));
}

__device__ __forceinline__ void split_bf16(float v, unsigned short* h, unsigned short* l) {
  unsigned int hb = __float_as_uint(v) >> 16;
  float r = v - __uint_as_float(hb << 16);
  *h = (unsigned short)hb;
  *l = (unsigned short)(__float_as_uint(r) >> 16);
}

__global__ void k_wsq(float* __restrict__ wsq) {
  int p = blockIdx.x * 256 + threadIdx.x;
  if (p >= XPLEN) return;
  int t0 = (p <= 511) ? 0 : (p - 352) / 160;
  int t1 = p / 160; if (t1 > 600) t1 = 600;
  float s = 0.f;
  for (int t = t0; t <= t1; t++) { float w = winval(p - t * HOP); s += w * w; }
  wsq[p] = s;
}

// BF split: Bt[n][k] = DFT-forward[k][n]
__global__ void k_bfsplit(unsigned short* __restrict__ H, unsigned short* __restrict__ L) {
  int idx = blockIdx.x * 256 + threadIdx.x;
  if (idx >= 640 * KPAD) return;
  int n = idx / KPAD, k = idx - n * KPAD;
  float v = 0.f;
  if (n < DD && k < NFFT) {
    float w = winval(k);
    int f = (n < NF) ? n : n - NF;
    int m = (k * f) & 511;
    float th = (float)(M_PI / 256.0) * (float)m;
    v = ((n < NF) ? cosf(th) : -sinf(th)) * w;
  }
  split_bf16(v, &H[idx], &L[idx]);
}

// WT split: Bt[n][k] = Wih[n][k]
__global__ void k_wtsplit(const float* __restrict__ Wih, unsigned short* __restrict__ H,
                          unsigned short* __restrict__ L) {
  int idx = blockIdx.x * 256 + threadIdx.x;
  if (idx >= G4 * KPAD) return;
  int n = idx / KPAD, k = idx - n * KPAD;
  float v = (k < DD) ? Wih[n * DD + k] : 0.f;
  split_bf16(v, &H[idx], &L[idx]);
}

// BI split: Bt[n][kk] = BI[kk][n]
__global__ void k_bisplit(unsigned short* __restrict__ H, unsigned short* __restrict__ L) {
  int idx = blockIdx.x * 256 + threadIdx.x;
  if (idx >= NFFT * KPAD) return;
  int n = idx / KPAD, kk = idx - n * KPAD;
  float v = 0.f;
  if (kk < DD) {
    float w = winval(n);
    int f = (kk < NF) ? kk : kk - NF;
    int edge = (f == 0 || f == 256);
    float alpha = edge ? 1.f : 2.f;
    int m = (n * f) & 511;
    float th = (float)(M_PI / 256.0) * (float)m;
    float c;
    if (kk < NF) c = alpha * cosf(th);
    else         c = edge ? 0.f : -alpha * sinf(th);
    v = c * w * (1.f / 512.f);
  }
  split_bf16(v, &H[idx], &L[idx]);
}

__global__ void k_wtrans(const float* __restrict__ bih, const float* __restrict__ bhh,
                         const float* __restrict__ W1, const float* __restrict__ W2,
                         float* __restrict__ BSUM, float* __restrict__ W1T, float* __restrict__ W2T) {
  int idx = blockIdx.x * 256 + threadIdx.x;
  if (idx < G4) BSUM[idx] = bih[idx] + bhh[idx];
  if (idx < HH * DD) { int h = idx / DD, j = idx - h * DD; W1T[idx] = W1[j * HH + h]; W2T[idx] = W2[j * HH + h]; }
}

// pack Whh rows into f16 pairs, TRANSPOSED: WhhPT[k2 * 512 + j] = (f16(W[j][2k2]), f16(W[j][2k2+1]))
__global__ void k_wpack(const float* __restrict__ Whh, unsigned int* __restrict__ WhhPT) {
  int idx = blockIdx.x * 256 + threadIdx.x;
  if (idx >= G4 * 64) return;
  int j = idx >> 6, k2 = idx & 63;
  _Float16 lo = (_Float16)Whh[j * HH + 2 * k2];
  _Float16 hi = (_Float16)Whh[j * HH + 2 * k2 + 1];
  unsigned int u = ((unsigned int)__builtin_bit_cast(unsigned short, hi) << 16)
                 |  (unsigned int)__builtin_bit_cast(unsigned short, lo);
  WhhPT[k2 * G4 + j] = u;
}

// reflect-padded multichannel extraction: XP[n][i], n=b*8+c
__global__ void k_xp(const float* __restrict__ x, float* __restrict__ XP) {
  int idx = blockIdx.x * 256 + threadIdx.x;
  if (idx >= NSEQ * XPLEN) return;
  int n = idx / XPLEN, i = idx - n * XPLEN;
  int j = i - FPAD;
  if (j < 0) j = -j;
  else if (j >= LSEQ) j = 2 * LSEQ - 2 - j;
  int b = n >> 3, c = n & 7;
  XP[idx] = x[((long)b * LSEQ + j) * NCH + c];
}

// ---------------- split-bf16 MFMA GEMM: C[M,N] = A[M,K] * Bt^T (+bias) ----------------
template <int GATHER>
__launch_bounds__(256)
__global__ void k_gemm3(const float* __restrict__ A,
                        const unsigned short* __restrict__ Bth,
                        const unsigned short* __restrict__ Btl,
                        const float* __restrict__ bias, float* __restrict__ C,
                        int M, int N, int K, int lda, int ldc) {
  __shared__ __align__(16) unsigned short sAh[128 * 40];
  __shared__ __align__(16) unsigned short sAl[128 * 40];
  __shared__ __align__(16) unsigned short sBh[128 * 40];
  __shared__ __align__(16) unsigned short sBl[128 * 40];
  const int tid = threadIdx.x;
  const int row0 = blockIdx.y * 128, col0 = blockIdx.x * 128;
  const int sar = tid >> 1, sak = (tid & 1) * 16;
  const int arow = row0 + sar;
  long abase;
  if (GATHER) { int nn = arow / TT; int t = arow - nn * TT; abase = (long)nn * XPLEN + (long)t * HOP; }
  else        { abase = (long)arow * lda; }
  const bool arok = (arow < M);
  const int lane = tid & 63, w = tid >> 6;
  const int wm = (w >> 1) * 64, wn = (w & 1) * 64;
  const int l15 = lane & 15, quad = lane >> 4;
  f32x4 acc[4][4] = {};
  unsigned int* aH = (unsigned int*)sAh;
  unsigned int* aL = (unsigned int*)sAl;
  uint4* bH = (uint4*)sBh;
  uint4* bL = (uint4*)sBl;
  for (int k0 = 0; k0 < K; k0 += 32) {
#pragma unroll
    for (int i = 0; i < 8; i++) {
      int kk = k0 + sak + 2 * i;
      float v0 = 0.f, v1 = 0.f;
      if (arok) {
        if (kk + 1 < K) { float2 t2 = *(const float2*)(A + abase + kk); v0 = t2.x; v1 = t2.y; }
        else if (kk < K) { v0 = A[abase + kk]; }
      }
      unsigned int h0 = __float_as_uint(v0) >> 16, h1 = __float_as_uint(v1) >> 16;
      float r0 = v0 - __uint_as_float(h0 << 16), r1 = v1 - __uint_as_float(h1 << 16);
      unsigned int l0 = __float_as_uint(r0) >> 16, l1 = __float_as_uint(r1) >> 16;
      aH[sar * 20 + (sak >> 1) + i] = h0 | (h1 << 16);
      aL[sar * 20 + (sak >> 1) + i] = l0 | (l1 << 16);
    }
#pragma unroll
    for (int h = 0; h < 2; h++) {
      int idx = tid + h * 256;
      int r = idx >> 2, c = idx & 3;
      long go = (long)(col0 + r) * KPAD + k0 + c * 8;
      bH[r * 5 + c] = *(const uint4*)(Bth + go);
      bL[r * 5 + c] = *(const uint4*)(Btl + go);
    }
    __syncthreads();
    bf16x8 ah[4], al[4], bh[4], bl[4];
#pragma unroll
    for (int i = 0; i < 4; i++) {
      int off = (wm + i * 16 + l15) * 40 + quad * 8;
      ah[i] = *(const bf16x8*)(sAh + off);
      al[i] = *(const bf16x8*)(sAl + off);
      int boff = (wn + i * 16 + l15) * 40 + quad * 8;
      bh[i] = *(const bf16x8*)(sBh + boff);
      bl[i] = *(const bf16x8*)(sBl + boff);
    }
#pragma unroll
    for (int i = 0; i < 4; i++)
#pragma unroll
      for (int j = 0; j < 4; j++) {
        acc[i][j] = __builtin_amdgcn_mfma_f32_16x16x32_bf16(al[i], bh[j], acc[i][j], 0, 0, 0);
        acc[i][j] = __builtin_amdgcn_mfma_f32_16x16x32_bf16(ah[i], bl[j], acc[i][j], 0, 0, 0);
        acc[i][j] = __builtin_amdgcn_mfma_f32_16x16x32_bf16(ah[i], bh[j], acc[i][j], 0, 0, 0);
      }
    __syncthreads();
  }
#pragma unroll
  for (int i = 0; i < 4; i++)
#pragma unroll
    for (int j = 0; j < 4; j++) {
      int cc = col0 + wn + j * 16 + l15;
      if (cc >= N) continue;
      float bv = bias ? bias[cc] : 0.f;
#pragma unroll
      for (int rg = 0; rg < 4; rg++) {
        int rr = row0 + wm + i * 16 + quad * 4 + rg;
        if (rr < M) C[(long)rr * ldc + cc] = acc[i][j][rg] + bv;
      }
    }
}

// ---------------- LSTM v7: k-split, 1024 thr, 32 weight regs/thread ----------------
// r5-r8 lesson: RA remat-sinks 64-reg weight arrays (but granted 88 VGPRs in r8),
// and every refetch path (L2 2160cyc, LDS-b32 2970cyc) is >=5x the VALU floor.
// Halve per-thread weights to 32 regs: thread (gate j=tid&511, half p=tid>>9)
// computes half the dot; partials meet in LDS.
__device__ __forceinline__ float tanh_fast(float x) {
  float e = __expf(2.f * x);
  return 1.f - 2.f / (e + 1.f);
}

__launch_bounds__(1024, 4)
__global__ void k_lstm(const float* __restrict__ XW, const unsigned int* __restrict__ WhhPT,
                       float* __restrict__ Hout) {
  __shared__ float part[1024];
  __shared__ unsigned int hl2[64];   // h packed as 64 f16-pairs
  const int tid = threadIdx.x;
  const int j = tid & 511;           // gate
  const int p = tid >> 9;            // k-half (wave-uniform: waves are 64-aligned)
  const int n = blockIdx.x;
  const int lane = tid & 63;
  unsigned int wp[32];
#pragma unroll
  for (int i = 0; i < 32; i++) wp[i] = WhhPT[(p * 32 + i) * G4 + j];   // coalesced over j
  float cst = 0.f;
  if (tid < 64) hl2[tid] = 0u;
  const float* xwrow = XW + (long)n * TT * G4 + j;
  float xnext = (p == 0) ? xwrow[0] : 0.f;
  __syncthreads();
  for (int t = 0; t < TT; t++) {
    float xv = xnext;
    if (p == 0 && t + 1 < TT) xnext = xwrow[(t + 1) * G4];
    unsigned int vh = hl2[lane];
    float a0 = 0.f, a1 = 0.f;
#pragma unroll
    for (int q = 0; q < 16; q++) {
      unsigned int h0 = __builtin_amdgcn_readlane(vh, p * 32 + 2 * q);
      unsigned int h1 = __builtin_amdgcn_readlane(vh, p * 32 + 2 * q + 1);
      a0 = __builtin_amdgcn_fdot2(__builtin_bit_cast(h2v, h0), __builtin_bit_cast(h2v, wp[2 * q]),     a0, false);
      a1 = __builtin_amdgcn_fdot2(__builtin_bit_cast(h2v, h1), __builtin_bit_cast(h2v, wp[2 * q + 1]), a1, false);
    }
    part[tid] = a0 + a1 + xv;   // p=0 partial carries xv
    __syncthreads();
    if (tid < HH) {
      float gi = part[tid]       + part[512 + tid];
      float gf = part[128 + tid] + part[640 + tid];
      float gg = part[256 + tid] + part[768 + tid];
      float go = part[384 + tid] + part[896 + tid];
      float si = 1.f / (1.f + __expf(-gi));
      float sf = 1.f / (1.f + __expf(-gf));
      float so = 1.f / (1.f + __expf(-go));
      cst = sf * cst + si * tanh_fast(gg);
      float hv = so * tanh_fast(cst);
      ((_Float16*)hl2)[tid] = (_Float16)hv;
      Hout[((long)n * TT + t) * HH + tid] = hv;
    }
    __syncthreads();
  }
}

// ---------------- fused mask GEMM + complex-mask apply + transpose to MS[b][f][c][ri][t] ----------------
__launch_bounds__(256)
__global__ void k_maskms(const float* __restrict__ Hout, const float* __restrict__ WT,
                         const float* __restrict__ bias, const float* __restrict__ S,
                         float* __restrict__ MS) {
  __shared__ float As[16][68];
  __shared__ float Bs[16][68];
  __shared__ float Cs[64][68];
  __shared__ float SR[64][33];
  __shared__ float SI[64][33];
  const int tid = threadIdx.x;
  const int tx = tid & 15, ty = tid >> 4;
  const int f0 = blockIdx.x * 32;
  const int row0 = blockIdx.y * 64;
  float acc[4][4] = {};
  const int ar = tid >> 2, ac = (tid & 3) * 4;
  const int bc = tid & 63, br = tid >> 6;
  const int r = row0 + ar;
  const int jb = bc & 31;
  const int fb = f0 + jb;
  const int fcolb = (bc < 32) ? fb : NF + fb;
  for (int k0 = 0; k0 < HH; k0 += 16) {
#pragma unroll
    for (int i = 0; i < 4; i++) As[ac + i][ar] = Hout[(long)r * HH + k0 + ac + i];
#pragma unroll
    for (int i = 0; i < 4; i++) {
      int kk = k0 + br + i * 4;
      Bs[br + i * 4][bc] = (fb < NF) ? WT[kk * DD + fcolb] : 0.f;
    }
    __syncthreads();
#pragma unroll
    for (int k = 0; k < 16; k++) {
      float4 av = *(const float4*)&As[k][ty * 4];
      float4 bv = *(const float4*)&Bs[k][tx * 4];
      float aa[4] = {av.x, av.y, av.z, av.w};
      float bb[4] = {bv.x, bv.y, bv.z, bv.w};
#pragma unroll
      for (int i = 0; i < 4; i++)
#pragma unroll
        for (int jj = 0; jj < 4; jj++) acc[i][jj] = fmaf(aa[i], bb[jj], acc[i][jj]);
    }
    __syncthreads();
  }
#pragma unroll
  for (int jj = 0; jj < 4; jj++) {
    int col = tx * 4 + jj;
    int f = f0 + (col & 31);
    int fcol = (col < 32) ? f : NF + f;
    float bv = (f < NF) ? bias[fcol] : 0.f;
#pragma unroll
    for (int i = 0; i < 4; i++) Cs[ty * 4 + i][col] = acc[i][jj] + bv;
  }
  __syncthreads();
  {
    int fl = tid & 31, r8 = tid >> 5;
    int f = f0 + fl;
#pragma unroll
    for (int i = 0; i < 8; i++) {
      int rl = r8 * 8 + i;
      int rr = row0 + rl;
      float rm = Cs[rl][fl], im = Cs[rl][32 + fl];
      float sr = 0.f, si = 0.f;
      if (f < NF) { sr = S[(long)rr * DD + f]; si = S[(long)rr * DD + NF + f]; }
      SR[rl][fl] = rm * sr - im * si;
      SI[rl][fl] = rm * si + im * sr;
    }
  }
  __syncthreads();
  {
    int tl = tid & 63, fq = tid >> 6;
    int rr = row0 + tl;
    int n = rr / TT, t = rr - n * TT;
    int b = n >> 3, c = n & 7;
#pragma unroll
    for (int i = 0; i < 8; i++) {
      int fl = fq * 8 + i;
      int f = f0 + fl;
      if (f < NF) {
        long addr = ((((long)b * NF + f) * 8 + c) * 2) * TT + t;
        MS[addr] = SR[tl][fl];
        MS[addr + TT] = SI[tl][fl];
      }
    }
  }
}

// ---------------- PSD: one block per (b,f) ----------------
__launch_bounds__(256)
__global__ void k_psd(const float* __restrict__ MS, float* __restrict__ PSD) {
  __shared__ float buf[9616];
  __shared__ float part[64][8];
  const int tid = threadIdx.x;
  const long base = (long)blockIdx.x * 9616;
  for (int i = tid; i < 9616; i += 256) buf[i] = MS[base + i];
  __syncthreads();
  int p = tid & 63, q = tid >> 6;
  int c = p >> 3, e = p & 7;
  const float* xc = &buf[c * 1202];
  const float* xe = &buf[e * 1202];
  int t0 = q * 150, t1 = (q == 3) ? TT : t0 + 150;
  float ar = 0.f, ai = 0.f;
  for (int t = t0; t < t1; t++) {
    float cr = xc[t], ci = xc[TT + t];
    float er = xe[t], ei = xe[TT + t];
    ar += cr * er + ci * ei;
    ai += ci * er - cr * ei;
  }
  part[p][q * 2] = ar; part[p][q * 2 + 1] = ai;
  __syncthreads();
  if (tid < 64) {
    float sr = part[tid][0] + part[tid][2] + part[tid][4] + part[tid][6];
    float si = part[tid][1] + part[tid][3] + part[tid][5] + part[tid][7];
    PSD[((long)blockIdx.x * 64 + tid) * 2]     = sr * (1.f / 601.f);
    PSD[((long)blockIdx.x * 64 + tid) * 2 + 1] = si * (1.f / 601.f);
  }
}

// ---------------- 8x8 complex solve + MVDR weight ----------------
__launch_bounds__(64)
__global__ void k_solve(const float* __restrict__ PS, const float* __restrict__ PN,
                        float* __restrict__ WV) {
  int idx = blockIdx.x * 64 + threadIdx.x;
  if (idx >= NB * NF) return;
  float Ar[8][8], Ai[8][8], Br[8][8], Bi[8][8];
  const float* pn = PN + (long)idx * 128;
  const float* ps = PS + (long)idx * 128;
  for (int i = 0; i < 8; i++)
    for (int j = 0; j < 8; j++) {
      Ar[i][j] = pn[(i * 8 + j) * 2]; Ai[i][j] = pn[(i * 8 + j) * 2 + 1];
      Br[i][j] = ps[(i * 8 + j) * 2]; Bi[i][j] = ps[(i * 8 + j) * 2 + 1];
    }
  float tr = 0.f;
  for (int i = 0; i < 8; i++) tr += Ar[i][i];
  float load = 1e-6f * tr / 8.f + 1e-8f;
  for (int i = 0; i < 8; i++) Ar[i][i] += load;
  for (int k = 0; k < 8; k++) {
    int piv = k; float mx = Ar[k][k] * Ar[k][k] + Ai[k][k] * Ai[k][k];
    for (int i = k + 1; i < 8; i++) {
      float m2 = Ar[i][k] * Ar[i][k] + Ai[i][k] * Ai[i][k];
      if (m2 > mx) { mx = m2; piv = i; }
    }
    if (piv != k) {
      for (int j = 0; j < 8; j++) {
        float t0;
        t0 = Ar[k][j]; Ar[k][j] = Ar[piv][j]; Ar[piv][j] = t0;
        t0 = Ai[k][j]; Ai[k][j] = Ai[piv][j]; Ai[piv][j] = t0;
        t0 = Br[k][j]; Br[k][j] = Br[piv][j]; Br[piv][j] = t0;
        t0 = Bi[k][j]; Bi[k][j] = Bi[piv][j]; Bi[piv][j] = t0;
      }
    }
    float dr = Ar[k][k], di = Ai[k][k];
    float inv = 1.f / (dr * dr + di * di);
    float irr = dr * inv, iii = -di * inv;
    for (int j = 0; j < 8; j++) {
      float xr = Ar[k][j], xi = Ai[k][j];
      Ar[k][j] = xr * irr - xi * iii; Ai[k][j] = xr * iii + xi * irr;
      xr = Br[k][j]; xi = Bi[k][j];
      Br[k][j] = xr * irr - xi * iii; Bi[k][j] = xr * iii + xi * irr;
    }
    for (int i = 0; i < 8; i++) {
      if (i == k) continue;
      float fr = Ar[i][k], fi = Ai[i][k];
      for (int j = 0; j < 8; j++) {
        float kr = Ar[k][j], ki = Ai[k][j];
        Ar[i][j] -= fr * kr - fi * ki;
        Ai[i][j] -= fr * ki + fi * kr;
        kr = Br[k][j]; ki = Bi[k][j];
        Br[i][j] -= fr * kr - fi * ki;
        Bi[i][j] -= fr * ki + fi * kr;
      }
    }
  }
  float trr = 1e-8f, tri = 0.f;
  for (int i = 0; i < 8; i++) { trr += Br[i][i]; tri += Bi[i][i]; }
  float inv = 1.f / (trr * trr + tri * tri);
  for (int c = 0; c < 8; c++) {
    float xr = Br[c][0], xi = Bi[c][0];
    WV[((long)idx * 8 + c) * 2]     = (xr * trr + xi * tri) * inv;
    WV[((long)idx * 8 + c) * 2 + 1] = (xi * trr - xr * tri) * inv;
  }
}

// ---------------- beamform ----------------
__launch_bounds__(320)
__global__ void k_beam(const float* __restrict__ S, const float* __restrict__ WV,
                       float* __restrict__ ENH) {
  __shared__ float WL[NF * 16];
  int bb = blockIdx.x / TT, t = blockIdx.x - bb * TT;
  for (int i = threadIdx.x; i < NF * 16; i += 320) WL[i] = WV[(long)bb * NF * 16 + i];
  __syncthreads();
  int f = threadIdx.x;
  if (f >= NF) return;
  float er = 0.f, ei = 0.f;
#pragma unroll
  for (int c = 0; c < 8; c++) {
    float wr = WL[(f * 8 + c) * 2], wi = WL[(f * 8 + c) * 2 + 1];
    const float* srow = S + (((long)(bb * 8 + c) * TT) + t) * DD;
    float sr = srow[f], si = srow[NF + f];
    er += wr * sr + wi * si;
    ei += wr * si - wi * sr;
  }
  float* erow = ENH + ((long)bb * TT + t) * DD;
  erow[f] = er;
  erow[NF + f] = ei;
}

// ---------------- overlap-add + normalize + crop ----------------
__global__ void k_ola(const float* __restrict__ IFR, const float* __restrict__ WSQ,
                      float* __restrict__ out) {
  int idx = blockIdx.x * 256 + threadIdx.x;
  if (idx >= NB * LSEQ) return;
  int b = idx / LSEQ, l = idx - b * LSEQ;
  int p = l + FPAD;
  int t0 = (p <= 511) ? 0 : (p - 352) / 160;
  int t1 = p / 160; if (t1 > 600) t1 = 600;
  float s = 0.f;
  for (int t = t0; t <= t1; t++) s += IFR[((long)b * TT + t) * NFFT + (p - t * HOP)];
  out[idx] = s / fmaxf(WSQ[p], 1e-11f);
}

// ---------------- driver ----------------
extern "C" void kernel_launch(void* const* d_in, const int* in_sizes, int n_in,
                              void* d_out, int out_size, void* d_ws, size_t ws_size,
                              hipStream_t stream) {
  (void)in_sizes; (void)n_in; (void)out_size; (void)ws_size;
  const float* x   = (const float*)d_in[0];
  const float* Wih = (const float*)d_in[1];
  const float* Whh = (const float*)d_in[2];
  const float* bih = (const float*)d_in[3];
  const float* bhh = (const float*)d_in[4];
  const float* W1  = (const float*)d_in[5];
  const float* b1  = (const float*)d_in[6];
  const float* W2  = (const float*)d_in[7];
  const float* b2  = (const float*)d_in[8];
  float* ws = (float*)d_ws;

  float* XP    = ws + 0;          // 6,176,768 (later IFR)
  float* S     = ws + 6176768;    // 19,774,496
  float* XWM   = ws + 25951264;   // 19,774,496 (XW then MS; WhhPT in tail)
  float* HOUT  = ws + 45725760;   // 4,924,288 (later ENH)
  float* PSD_S = ws + 50650048;   // 263,168
  float* PSD_N = ws + 50913216;   // 263,168
  float* WV    = ws + 51176384;   // 32,896
  float* W1T   = ws + 51209280;   // 65,792
  float* W2T   = ws + 51275072;   // 65,792
  float* BSUM  = ws + 51340864;   // 512
  float* WSQ   = ws + 51341376;   // 96,512 -> 51,437,888
  unsigned short* BFth = (unsigned short*)(ws + 51437888);
  unsigned short* BFtl = (unsigned short*)(ws + 51611968);
  unsigned short* WTth = (unsigned short*)(ws + 51786048);
  unsigned short* WTtl = (unsigned short*)(ws + 51925312);
  unsigned short* BIth = (unsigned short*)(ws + 52064576);
  unsigned short* BItl = (unsigned short*)(ws + 52203840); // -> end 52,343,104 (~199.7MB)
  float* MS    = XWM;
  float* ENH   = HOUT;
  float* IFR   = XP;
  unsigned int* WhhPT = (unsigned int*)(XWM + 19693568);   // after true end of XW

  k_wsq<<<(XPLEN + 255) / 256, 256, 0, stream>>>(WSQ);
  k_bfsplit<<<(640 * KPAD + 255) / 256, 256, 0, stream>>>(BFth, BFtl);
  k_wtsplit<<<(G4 * KPAD + 255) / 256, 256, 0, stream>>>(Wih, WTth, WTtl);
  k_bisplit<<<(NFFT * KPAD + 255) / 256, 256, 0, stream>>>(BIth, BItl);
  k_wtrans<<<(HH * DD + 255) / 256, 256, 0, stream>>>(bih, bhh, W1, W2, BSUM, W1T, W2T);
  k_wpack<<<(G4 * 64 + 255) / 256, 256, 0, stream>>>(Whh, WhhPT);
  k_xp<<<(NSEQ * XPLEN + 255) / 256, 256, 0, stream>>>(x, XP);

  // STFT: S[38464,514] = frames(XP) @ BF
  {
    dim3 g(5, 301);
    k_gemm3<1><<<g, 256, 0, stream>>>(XP, BFth, BFtl, nullptr, S, NROWS, DD, NFFT, 0, DD);
  }
  // xW: XWM[38464,512] = S @ Wih^T + bsum
  {
    dim3 g(4, 301);
    k_gemm3<0><<<g, 256, 0, stream>>>(S, WTth, WTtl, BSUM, XWM, NROWS, G4, DD, DD, G4);
  }

  k_lstm<<<64, 1024, 0, stream>>>(XWM, WhhPT, HOUT);

  dim3 gm(9, 601);
  k_maskms<<<gm, 256, 0, stream>>>(HOUT, W1T, b1, S, MS);
  k_psd<<<NB * NF, 256, 0, stream>>>(MS, PSD_S);
  k_maskms<<<gm, 256, 0, stream>>>(HOUT, W2T, b2, S, MS);
  k_psd<<<NB * NF, 256, 0, stream>>>(MS, PSD_N);

  k_solve<<<(NB * NF + 63) / 64, 64, 0, stream>>>(PSD_S, PSD_N, WV);
  k_beam<<<NB * TT, 320, 0, stream>>>(S, WV, ENH);

  // iSTFT: IFR[4808,512] = ENH @ BI
  {
    dim3 g(4, 38);
    k_gemm3<0><<<g, 256, 0, stream>>>(ENH, BIth, BItl, nullptr, IFR, NB * TT, NFFT, DD, DD, NFFT);
  }

  k_ola<<<(NB * LSEQ + 255) / 256, 256, 0, stream>>>(IFR, WSQ, (float*)d_out);
}

// Round 10
// 1482.144 us; speedup vs baseline: 1.2017x; 1.2017x over previous
//
#include <hip/hip_runtime.h>
#include <math.h>

#define NFFT  512
#define WINL  320
#define HOP   160
#define FPAD  256
#define NF    257
#define TT    601
#define LSEQ  96000
#define XPLEN 96512
#define NCH   8
#define NB    8
#define NSEQ  64
#define NROWS 38464   // NSEQ*TT
#define DD    514
#define HH    128
#define G4    512
#define KPAD  544     // 17*32, zero-padded K for split-B arrays

typedef _Float16 h2v __attribute__((ext_vector_type(2)));
typedef short bf16x8 __attribute__((ext_vector_type(8)));
typedef float f32x4 __attribute__((ext_vector_type(4)));

// ---------------- init helpers ----------------
__device__ __forceinline__ float winval(int k) {
  if (k < 96 || k >= 416) return 0.f;
  return 0.5f - 0.5f * cosf((float)(2.0 * M_PI / 320.0) * (float)(k - 96));
}

__device__ __forceinline__ void split_bf16(float v, unsigned short* h, unsigned short* l) {
  unsigned int hb = __float_as_uint(v) >> 16;
  float r = v - __uint_as_float(hb << 16);
  *h = (unsigned short)hb;
  *l = (unsigned short)(__float_as_uint(r) >> 16);
}

__global__ void k_wsq(float* __restrict__ wsq) {
  int p = blockIdx.x * 256 + threadIdx.x;
  if (p >= XPLEN) return;
  int t0 = (p <= 511) ? 0 : (p - 352) / 160;
  int t1 = p / 160; if (t1 > 600) t1 = 600;
  float s = 0.f;
  for (int t = t0; t <= t1; t++) { float w = winval(p - t * HOP); s += w * w; }
  wsq[p] = s;
}

// BF split: Bt[n][k] = DFT-forward[k][n]
__global__ void k_bfsplit(unsigned short* __restrict__ H, unsigned short* __restrict__ L) {
  int idx = blockIdx.x * 256 + threadIdx.x;
  if (idx >= 640 * KPAD) return;
  int n = idx / KPAD, k = idx - n * KPAD;
  float v = 0.f;
  if (n < DD && k < NFFT) {
    float w = winval(k);
    int f = (n < NF) ? n : n - NF;
    int m = (k * f) & 511;
    float th = (float)(M_PI / 256.0) * (float)m;
    v = ((n < NF) ? cosf(th) : -sinf(th)) * w;
  }
  split_bf16(v, &H[idx], &L[idx]);
}

// WT split: Bt[n][k] = Wih[n][k]
__global__ void k_wtsplit(const float* __restrict__ Wih, unsigned short* __restrict__ H,
                          unsigned short* __restrict__ L) {
  int idx = blockIdx.x * 256 + threadIdx.x;
  if (idx >= G4 * KPAD) return;
  int n = idx / KPAD, k = idx - n * KPAD;
  float v = (k < DD) ? Wih[n * DD + k] : 0.f;
  split_bf16(v, &H[idx], &L[idx]);
}

// BI split: Bt[n][kk] = BI[kk][n]
__global__ void k_bisplit(unsigned short* __restrict__ H, unsigned short* __restrict__ L) {
  int idx = blockIdx.x * 256 + threadIdx.x;
  if (idx >= NFFT * KPAD) return;
  int n = idx / KPAD, kk = idx - n * KPAD;
  float v = 0.f;
  if (kk < DD) {
    float w = winval(n);
    int f = (kk < NF) ? kk : kk - NF;
    int edge = (f == 0 || f == 256);
    float alpha = edge ? 1.f : 2.f;
    int m = (n * f) & 511;
    float th = (float)(M_PI / 256.0) * (float)m;
    float c;
    if (kk < NF) c = alpha * cosf(th);
    else         c = edge ? 0.f : -alpha * sinf(th);
    v = c * w * (1.f / 512.f);
  }
  split_bf16(v, &H[idx], &L[idx]);
}

__global__ void k_wtrans(const float* __restrict__ bih, const float* __restrict__ bhh,
                         const float* __restrict__ W1, const float* __restrict__ W2,
                         float* __restrict__ BSUM, float* __restrict__ W1T, float* __restrict__ W2T) {
  int idx = blockIdx.x * 256 + threadIdx.x;
  if (idx < G4) BSUM[idx] = bih[idx] + bhh[idx];
  if (idx < HH * DD) { int h = idx / DD, j = idx - h * DD; W1T[idx] = W1[j * HH + h]; W2T[idx] = W2[j * HH + h]; }
}

// pack Whh into f16 pairs, uint4-transposed: flat index (k2>>2)*2048 + j*4 + (k2&3)
// -> thread j reads uint4 at (i4*512 + j): lane-coalesced AND 16B-vectorized.
__global__ void k_wpack(const float* __restrict__ Whh, unsigned int* __restrict__ WhhP4) {
  int idx = blockIdx.x * 256 + threadIdx.x;
  if (idx >= G4 * 64) return;
  int j = idx >> 6, k2 = idx & 63;
  _Float16 lo = (_Float16)Whh[j * HH + 2 * k2];
  _Float16 hi = (_Float16)Whh[j * HH + 2 * k2 + 1];
  unsigned int u = ((unsigned int)__builtin_bit_cast(unsigned short, hi) << 16)
                 |  (unsigned int)__builtin_bit_cast(unsigned short, lo);
  WhhP4[(k2 >> 2) * (G4 * 4) + j * 4 + (k2 & 3)] = u;
}

// reflect-padded multichannel extraction: XP[n][i], n=b*8+c
__global__ void k_xp(const float* __restrict__ x, float* __restrict__ XP) {
  int idx = blockIdx.x * 256 + threadIdx.x;
  if (idx >= NSEQ * XPLEN) return;
  int n = idx / XPLEN, i = idx - n * XPLEN;
  int j = i - FPAD;
  if (j < 0) j = -j;
  else if (j >= LSEQ) j = 2 * LSEQ - 2 - j;
  int b = n >> 3, c = n & 7;
  XP[idx] = x[((long)b * LSEQ + j) * NCH + c];
}

// ---------------- split-bf16 MFMA GEMM: C[M,N] = A[M,K] * Bt^T (+bias) ----------------
template <int GATHER>
__launch_bounds__(256)
__global__ void k_gemm3(const float* __restrict__ A,
                        const unsigned short* __restrict__ Bth,
                        const unsigned short* __restrict__ Btl,
                        const float* __restrict__ bias, float* __restrict__ C,
                        int M, int N, int K, int lda, int ldc) {
  __shared__ __align__(16) unsigned short sAh[128 * 40];
  __shared__ __align__(16) unsigned short sAl[128 * 40];
  __shared__ __align__(16) unsigned short sBh[128 * 40];
  __shared__ __align__(16) unsigned short sBl[128 * 40];
  const int tid = threadIdx.x;
  const int row0 = blockIdx.y * 128, col0 = blockIdx.x * 128;
  const int sar = tid >> 1, sak = (tid & 1) * 16;
  const int arow = row0 + sar;
  long abase;
  if (GATHER) { int nn = arow / TT; int t = arow - nn * TT; abase = (long)nn * XPLEN + (long)t * HOP; }
  else        { abase = (long)arow * lda; }
  const bool arok = (arow < M);
  const int lane = tid & 63, w = tid >> 6;
  const int wm = (w >> 1) * 64, wn = (w & 1) * 64;
  const int l15 = lane & 15, quad = lane >> 4;
  f32x4 acc[4][4] = {};
  unsigned int* aH = (unsigned int*)sAh;
  unsigned int* aL = (unsigned int*)sAl;
  uint4* bH = (uint4*)sBh;
  uint4* bL = (uint4*)sBl;
  for (int k0 = 0; k0 < K; k0 += 32) {
#pragma unroll
    for (int i = 0; i < 8; i++) {
      int kk = k0 + sak + 2 * i;
      float v0 = 0.f, v1 = 0.f;
      if (arok) {
        if (kk + 1 < K) { float2 t2 = *(const float2*)(A + abase + kk); v0 = t2.x; v1 = t2.y; }
        else if (kk < K) { v0 = A[abase + kk]; }
      }
      unsigned int h0 = __float_as_uint(v0) >> 16, h1 = __float_as_uint(v1) >> 16;
      float r0 = v0 - __uint_as_float(h0 << 16), r1 = v1 - __uint_as_float(h1 << 16);
      unsigned int l0 = __float_as_uint(r0) >> 16, l1 = __float_as_uint(r1) >> 16;
      aH[sar * 20 + (sak >> 1) + i] = h0 | (h1 << 16);
      aL[sar * 20 + (sak >> 1) + i] = l0 | (l1 << 16);
    }
#pragma unroll
    for (int h = 0; h < 2; h++) {
      int idx = tid + h * 256;
      int r = idx >> 2, c = idx & 3;
      long go = (long)(col0 + r) * KPAD + k0 + c * 8;
      bH[r * 5 + c] = *(const uint4*)(Bth + go);
      bL[r * 5 + c] = *(const uint4*)(Btl + go);
    }
    __syncthreads();
    bf16x8 ah[4], al[4], bh[4], bl[4];
#pragma unroll
    for (int i = 0; i < 4; i++) {
      int off = (wm + i * 16 + l15) * 40 + quad * 8;
      ah[i] = *(const bf16x8*)(sAh + off);
      al[i] = *(const bf16x8*)(sAl + off);
      int boff = (wn + i * 16 + l15) * 40 + quad * 8;
      bh[i] = *(const bf16x8*)(sBh + boff);
      bl[i] = *(const bf16x8*)(sBl + boff);
    }
#pragma unroll
    for (int i = 0; i < 4; i++)
#pragma unroll
      for (int j = 0; j < 4; j++) {
        acc[i][j] = __builtin_amdgcn_mfma_f32_16x16x32_bf16(al[i], bh[j], acc[i][j], 0, 0, 0);
        acc[i][j] = __builtin_amdgcn_mfma_f32_16x16x32_bf16(ah[i], bl[j], acc[i][j], 0, 0, 0);
        acc[i][j] = __builtin_amdgcn_mfma_f32_16x16x32_bf16(ah[i], bh[j], acc[i][j], 0, 0, 0);
      }
    __syncthreads();
  }
#pragma unroll
  for (int i = 0; i < 4; i++)
#pragma unroll
    for (int j = 0; j < 4; j++) {
      int cc = col0 + wn + j * 16 + l15;
      if (cc >= N) continue;
      float bv = bias ? bias[cc] : 0.f;
#pragma unroll
      for (int rg = 0; rg < 4; rg++) {
        int rr = row0 + wm + i * 16 + quad * 4 + rg;
        if (rr < M) C[(long)rr * ldc + cc] = acc[i][j][rg] + bv;
      }
    }
}

// ---------------- LSTM v8: r5 structure + uint4-transposed coalesced weight refetch ----------------
// RA remat-sinks the weight loads no matter what (r3/r5/r7/r9) -> accept refetch,
// make each sunk load a lane-coalesced dwordx4 (1 KB/wave-inst contiguous) instead of
// r5's 64-line scatter. 16 dwordx4/thread/step, compute loop identical to r5.
__device__ __forceinline__ float tanh_fast(float x) {
  float e = __expf(2.f * x);
  return 1.f - 2.f / (e + 1.f);
}

__launch_bounds__(512, 2)
__global__ void k_lstm(const float* __restrict__ XW, const unsigned int* __restrict__ WhhP4,
                       float* __restrict__ Hout) {
  __shared__ unsigned int hl2[64];   // h packed as 64 f16-pairs
  __shared__ float gl[G4];
  const int j = threadIdx.x;
  const int n = blockIdx.x;
  const uint4* W4 = (const uint4*)WhhP4;   // uint4 index i4*512 + j : coalesced over j
  unsigned int wp[64];
#pragma unroll
  for (int i4 = 0; i4 < 16; i4++) {
    uint4 v = W4[i4 * G4 + j];
    wp[4 * i4]     = v.x;
    wp[4 * i4 + 1] = v.y;
    wp[4 * i4 + 2] = v.z;
    wp[4 * i4 + 3] = v.w;
  }
  float cst = 0.f;
  if (j < 64) hl2[j] = 0u;
  const float* xwrow = XW + (long)n * TT * G4 + j;
  const int lane = j & 63;
  float xnext = xwrow[0];
  __syncthreads();
  for (int t = 0; t < TT; t++) {
    float xv = xnext;
    if (t + 1 < TT) xnext = xwrow[(t + 1) * G4];
    unsigned int vh = hl2[lane];
    float a0 = 0.f, a1 = 0.f, a2 = 0.f, a3 = 0.f;
#pragma unroll
    for (int q = 0; q < 16; q++) {
      unsigned int p0 = __builtin_amdgcn_readlane(vh, 4 * q);
      unsigned int p1 = __builtin_amdgcn_readlane(vh, 4 * q + 1);
      unsigned int p2 = __builtin_amdgcn_readlane(vh, 4 * q + 2);
      unsigned int p3 = __builtin_amdgcn_readlane(vh, 4 * q + 3);
      a0 = __builtin_amdgcn_fdot2(__builtin_bit_cast(h2v, p0), __builtin_bit_cast(h2v, wp[4 * q]),     a0, false);
      a1 = __builtin_amdgcn_fdot2(__builtin_bit_cast(h2v, p1), __builtin_bit_cast(h2v, wp[4 * q + 1]), a1, false);
      a2 = __builtin_amdgcn_fdot2(__builtin_bit_cast(h2v, p2), __builtin_bit_cast(h2v, wp[4 * q + 2]), a2, false);
      a3 = __builtin_amdgcn_fdot2(__builtin_bit_cast(h2v, p3), __builtin_bit_cast(h2v, wp[4 * q + 3]), a3, false);
    }
    gl[j] = ((a0 + a1) + (a2 + a3)) + xv;
    __syncthreads();
    if (j < HH) {
      float gi = gl[j], gf = gl[HH + j], gg = gl[2 * HH + j], go = gl[3 * HH + j];
      float si = 1.f / (1.f + __expf(-gi));
      float sf = 1.f / (1.f + __expf(-gf));
      float so = 1.f / (1.f + __expf(-go));
      cst = sf * cst + si * tanh_fast(gg);
      float hv = so * tanh_fast(cst);
      ((_Float16*)hl2)[j] = (_Float16)hv;
      Hout[((long)n * TT + t) * HH + j] = hv;
    }
    __syncthreads();
  }
}

// ---------------- fused mask GEMM + complex-mask apply + transpose to MS[b][f][c][ri][t] ----------------
__launch_bounds__(256)
__global__ void k_maskms(const float* __restrict__ Hout, const float* __restrict__ WT,
                         const float* __restrict__ bias, const float* __restrict__ S,
                         float* __restrict__ MS) {
  __shared__ float As[16][68];
  __shared__ float Bs[16][68];
  __shared__ float Cs[64][68];
  __shared__ float SR[64][33];
  __shared__ float SI[64][33];
  const int tid = threadIdx.x;
  const int tx = tid & 15, ty = tid >> 4;
  const int f0 = blockIdx.x * 32;
  const int row0 = blockIdx.y * 64;
  float acc[4][4] = {};
  const int ar = tid >> 2, ac = (tid & 3) * 4;
  const int bc = tid & 63, br = tid >> 6;
  const int r = row0 + ar;
  const int jb = bc & 31;
  const int fb = f0 + jb;
  const int fcolb = (bc < 32) ? fb : NF + fb;
  for (int k0 = 0; k0 < HH; k0 += 16) {
#pragma unroll
    for (int i = 0; i < 4; i++) As[ac + i][ar] = Hout[(long)r * HH + k0 + ac + i];
#pragma unroll
    for (int i = 0; i < 4; i++) {
      int kk = k0 + br + i * 4;
      Bs[br + i * 4][bc] = (fb < NF) ? WT[kk * DD + fcolb] : 0.f;
    }
    __syncthreads();
#pragma unroll
    for (int k = 0; k < 16; k++) {
      float4 av = *(const float4*)&As[k][ty * 4];
      float4 bv = *(const float4*)&Bs[k][tx * 4];
      float aa[4] = {av.x, av.y, av.z, av.w};
      float bb[4] = {bv.x, bv.y, bv.z, bv.w};
#pragma unroll
      for (int i = 0; i < 4; i++)
#pragma unroll
        for (int jj = 0; jj < 4; jj++) acc[i][jj] = fmaf(aa[i], bb[jj], acc[i][jj]);
    }
    __syncthreads();
  }
#pragma unroll
  for (int jj = 0; jj < 4; jj++) {
    int col = tx * 4 + jj;
    int f = f0 + (col & 31);
    int fcol = (col < 32) ? f : NF + f;
    float bv = (f < NF) ? bias[fcol] : 0.f;
#pragma unroll
    for (int i = 0; i < 4; i++) Cs[ty * 4 + i][col] = acc[i][jj] + bv;
  }
  __syncthreads();
  {
    int fl = tid & 31, r8 = tid >> 5;
    int f = f0 + fl;
#pragma unroll
    for (int i = 0; i < 8; i++) {
      int rl = r8 * 8 + i;
      int rr = row0 + rl;
      float rm = Cs[rl][fl], im = Cs[rl][32 + fl];
      float sr = 0.f, si = 0.f;
      if (f < NF) { sr = S[(long)rr * DD + f]; si = S[(long)rr * DD + NF + f]; }
      SR[rl][fl] = rm * sr - im * si;
      SI[rl][fl] = rm * si + im * sr;
    }
  }
  __syncthreads();
  {
    int tl = tid & 63, fq = tid >> 6;
    int rr = row0 + tl;
    int n = rr / TT, t = rr - n * TT;
    int b = n >> 3, c = n & 7;
#pragma unroll
    for (int i = 0; i < 8; i++) {
      int fl = fq * 8 + i;
      int f = f0 + fl;
      if (f < NF) {
        long addr = ((((long)b * NF + f) * 8 + c) * 2) * TT + t;
        MS[addr] = SR[tl][fl];
        MS[addr + TT] = SI[tl][fl];
      }
    }
  }
}

// ---------------- PSD: one block per (b,f) ----------------
__launch_bounds__(256)
__global__ void k_psd(const float* __restrict__ MS, float* __restrict__ PSD) {
  __shared__ float buf[9616];
  __shared__ float part[64][8];
  const int tid = threadIdx.x;
  const long base = (long)blockIdx.x * 9616;
  for (int i = tid; i < 9616; i += 256) buf[i] = MS[base + i];
  __syncthreads();
  int p = tid & 63, q = tid >> 6;
  int c = p >> 3, e = p & 7;
  const float* xc = &buf[c * 1202];
  const float* xe = &buf[e * 1202];
  int t0 = q * 150, t1 = (q == 3) ? TT : t0 + 150;
  float ar = 0.f, ai = 0.f;
  for (int t = t0; t < t1; t++) {
    float cr = xc[t], ci = xc[TT + t];
    float er = xe[t], ei = xe[TT + t];
    ar += cr * er + ci * ei;
    ai += ci * er - cr * ei;
  }
  part[p][q * 2] = ar; part[p][q * 2 + 1] = ai;
  __syncthreads();
  if (tid < 64) {
    float sr = part[tid][0] + part[tid][2] + part[tid][4] + part[tid][6];
    float si = part[tid][1] + part[tid][3] + part[tid][5] + part[tid][7];
    PSD[((long)blockIdx.x * 64 + tid) * 2]     = sr * (1.f / 601.f);
    PSD[((long)blockIdx.x * 64 + tid) * 2 + 1] = si * (1.f / 601.f);
  }
}

// ---------------- 8x8 complex solve + MVDR weight ----------------
__launch_bounds__(64)
__global__ void k_solve(const float* __restrict__ PS, const float* __restrict__ PN,
                        float* __restrict__ WV) {
  int idx = blockIdx.x * 64 + threadIdx.x;
  if (idx >= NB * NF) return;
  float Ar[8][8], Ai[8][8], Br[8][8], Bi[8][8];
  const float* pn = PN + (long)idx * 128;
  const float* ps = PS + (long)idx * 128;
  for (int i = 0; i < 8; i++)
    for (int j = 0; j < 8; j++) {
      Ar[i][j] = pn[(i * 8 + j) * 2]; Ai[i][j] = pn[(i * 8 + j) * 2 + 1];
      Br[i][j] = ps[(i * 8 + j) * 2]; Bi[i][j] = ps[(i * 8 + j) * 2 + 1];
    }
  float tr = 0.f;
  for (int i = 0; i < 8; i++) tr += Ar[i][i];
  float load = 1e-6f * tr / 8.f + 1e-8f;
  for (int i = 0; i < 8; i++) Ar[i][i] += load;
  for (int k = 0; k < 8; k++) {
    int piv = k; float mx = Ar[k][k] * Ar[k][k] + Ai[k][k] * Ai[k][k];
    for (int i = k + 1; i < 8; i++) {
      float m2 = Ar[i][k] * Ar[i][k] + Ai[i][k] * Ai[i][k];
      if (m2 > mx) { mx = m2; piv = i; }
    }
    if (piv != k) {
      for (int j = 0; j < 8; j++) {
        float t0;
        t0 = Ar[k][j]; Ar[k][j] = Ar[piv][j]; Ar[piv][j] = t0;
        t0 = Ai[k][j]; Ai[k][j] = Ai[piv][j]; Ai[piv][j] = t0;
        t0 = Br[k][j]; Br[k][j] = Br[piv][j]; Br[piv][j] = t0;
        t0 = Bi[k][j]; Bi[k][j] = Bi[piv][j]; Bi[piv][j] = t0;
      }
    }
    float dr = Ar[k][k], di = Ai[k][k];
    float inv = 1.f / (dr * dr + di * di);
    float irr = dr * inv, iii = -di * inv;
    for (int j = 0; j < 8; j++) {
      float xr = Ar[k][j], xi = Ai[k][j];
      Ar[k][j] = xr * irr - xi * iii; Ai[k][j] = xr * iii + xi * irr;
      xr = Br[k][j]; xi = Bi[k][j];
      Br[k][j] = xr * irr - xi * iii; Bi[k][j] = xr * iii + xi * irr;
    }
    for (int i = 0; i < 8; i++) {
      if (i == k) continue;
      float fr = Ar[i][k], fi = Ai[i][k];
      for (int j = 0; j < 8; j++) {
        float kr = Ar[k][j], ki = Ai[k][j];
        Ar[i][j] -= fr * kr - fi * ki;
        Ai[i][j] -= fr * ki + fi * kr;
        kr = Br[k][j]; ki = Bi[k][j];
        Br[i][j] -= fr * kr - fi * ki;
        Bi[i][j] -= fr * ki + fi * kr;
      }
    }
  }
  float trr = 1e-8f, tri = 0.f;
  for (int i = 0; i < 8; i++) { trr += Br[i][i]; tri += Bi[i][i]; }
  float inv = 1.f / (trr * trr + tri * tri);
  for (int c = 0; c < 8; c++) {
    float xr = Br[c][0], xi = Bi[c][0];
    WV[((long)idx * 8 + c) * 2]     = (xr * trr + xi * tri) * inv;
    WV[((long)idx * 8 + c) * 2 + 1] = (xi * trr - xr * tri) * inv;
  }
}

// ---------------- beamform ----------------
__launch_bounds__(320)
__global__ void k_beam(const float* __restrict__ S, const float* __restrict__ WV,
                       float* __restrict__ ENH) {
  __shared__ float WL[NF * 16];
  int bb = blockIdx.x / TT, t = blockIdx.x - bb * TT;
  for (int i = threadIdx.x; i < NF * 16; i += 320) WL[i] = WV[(long)bb * NF * 16 + i];
  __syncthreads();
  int f = threadIdx.x;
  if (f >= NF) return;
  float er = 0.f, ei = 0.f;
#pragma unroll
  for (int c = 0; c < 8; c++) {
    float wr = WL[(f * 8 + c) * 2], wi = WL[(f * 8 + c) * 2 + 1];
    const float* srow = S + (((long)(bb * 8 + c) * TT) + t) * DD;
    float sr = srow[f], si = srow[NF + f];
    er += wr * sr + wi * si;
    ei += wr * si - wi * sr;
  }
  float* erow = ENH + ((long)bb * TT + t) * DD;
  erow[f] = er;
  erow[NF + f] = ei;
}

// ---------------- overlap-add + normalize + crop ----------------
__global__ void k_ola(const float* __restrict__ IFR, const float* __restrict__ WSQ,
                      float* __restrict__ out) {
  int idx = blockIdx.x * 256 + threadIdx.x;
  if (idx >= NB * LSEQ) return;
  int b = idx / LSEQ, l = idx - b * LSEQ;
  int p = l + FPAD;
  int t0 = (p <= 511) ? 0 : (p - 352) / 160;
  int t1 = p / 160; if (t1 > 600) t1 = 600;
  float s = 0.f;
  for (int t = t0; t <= t1; t++) s += IFR[((long)b * TT + t) * NFFT + (p - t * HOP)];
  out[idx] = s / fmaxf(WSQ[p], 1e-11f);
}

// ---------------- driver ----------------
extern "C" void kernel_launch(void* const* d_in, const int* in_sizes, int n_in,
                              void* d_out, int out_size, void* d_ws, size_t ws_size,
                              hipStream_t stream) {
  (void)in_sizes; (void)n_in; (void)out_size; (void)ws_size;
  const float* x   = (const float*)d_in[0];
  const float* Wih = (const float*)d_in[1];
  const float* Whh = (const float*)d_in[2];
  const float* bih = (const float*)d_in[3];
  const float* bhh = (const float*)d_in[4];
  const float* W1  = (const float*)d_in[5];
  const float* b1  = (const float*)d_in[6];
  const float* W2  = (const float*)d_in[7];
  const float* b2  = (const float*)d_in[8];
  float* ws = (float*)d_ws;

  float* XP    = ws + 0;          // 6,176,768 (later IFR)
  float* S     = ws + 6176768;    // 19,774,496
  float* XWM   = ws + 25951264;   // 19,774,496 (XW then MS; WhhP4 in tail)
  float* HOUT  = ws + 45725760;   // 4,924,288 (later ENH)
  float* PSD_S = ws + 50650048;   // 263,168
  float* PSD_N = ws + 50913216;   // 263,168
  float* WV    = ws + 51176384;   // 32,896
  float* W1T   = ws + 51209280;   // 65,792
  float* W2T   = ws + 51275072;   // 65,792
  float* BSUM  = ws + 51340864;   // 512
  float* WSQ   = ws + 51341376;   // 96,512 -> 51,437,888
  unsigned short* BFth = (unsigned short*)(ws + 51437888);
  unsigned short* BFtl = (unsigned short*)(ws + 51611968);
  unsigned short* WTth = (unsigned short*)(ws + 51786048);
  unsigned short* WTtl = (unsigned short*)(ws + 51925312);
  unsigned short* BIth = (unsigned short*)(ws + 52064576);
  unsigned short* BItl = (unsigned short*)(ws + 52203840); // -> end 52,343,104 (~199.7MB)
  float* MS    = XWM;
  float* ENH   = HOUT;
  float* IFR   = XP;
  unsigned int* WhhP4 = (unsigned int*)(XWM + 19693568);   // after true end of XW

  k_wsq<<<(XPLEN + 255) / 256, 256, 0, stream>>>(WSQ);
  k_bfsplit<<<(640 * KPAD + 255) / 256, 256, 0, stream>>>(BFth, BFtl);
  k_wtsplit<<<(G4 * KPAD + 255) / 256, 256, 0, stream>>>(Wih, WTth, WTtl);
  k_bisplit<<<(NFFT * KPAD + 255) / 256, 256, 0, stream>>>(BIth, BItl);
  k_wtrans<<<(HH * DD + 255) / 256, 256, 0, stream>>>(bih, bhh, W1, W2, BSUM, W1T, W2T);
  k_wpack<<<(G4 * 64 + 255) / 256, 256, 0, stream>>>(Whh, WhhP4);
  k_xp<<<(NSEQ * XPLEN + 255) / 256, 256, 0, stream>>>(x, XP);

  // STFT: S[38464,514] = frames(XP) @ BF
  {
    dim3 g(5, 301);
    k_gemm3<1><<<g, 256, 0, stream>>>(XP, BFth, BFtl, nullptr, S, NROWS, DD, NFFT, 0, DD);
  }
  // xW: XWM[38464,512] = S @ Wih^T + bsum
  {
    dim3 g(4, 301);
    k_gemm3<0><<<g, 256, 0, stream>>>(S, WTth, WTtl, BSUM, XWM, NROWS, G4, DD, DD, G4);
  }

  k_lstm<<<64, 512, 0, stream>>>(XWM, WhhP4, HOUT);

  dim3 gm(9, 601);
  k_maskms<<<gm, 256, 0, stream>>>(HOUT, W1T, b1, S, MS);
  k_psd<<<NB * NF, 256, 0, stream>>>(MS, PSD_S);
  k_maskms<<<gm, 256, 0, stream>>>(HOUT, W2T, b2, S, MS);
  k_psd<<<NB * NF, 256, 0, stream>>>(MS, PSD_N);

  k_solve<<<(NB * NF + 63) / 64, 64, 0, stream>>>(PSD_S, PSD_N, WV);
  k_beam<<<NB * TT, 320, 0, stream>>>(S, WV, ENH);

  // iSTFT: IFR[4808,512] = ENH @ BI
  {
    dim3 g(4, 38);
    k_gemm3<0><<<g, 256, 0, stream>>>(ENH, BIth, BItl, nullptr, IFR, NB * TT, NFFT, DD, DD, NFFT);
  }

  k_ola<<<(NB * LSEQ + 255) / 256, 256, 0, stream>>>(IFR, WSQ, (float*)d_out);
}

// Round 11
// 1404.821 us; speedup vs baseline: 1.2679x; 1.0550x over previous
//
#include <hip/hip_runtime.h>
#include <math.h>

#define NFFT  512
#define WINL  320
#define HOP   160
#define FPAD  256
#define NF    257
#define TT    601
#define LSEQ  96000
#define XPLEN 96512
#define NCH   8
#define NB    8
#define NSEQ  64
#define NROWS 38464   // NSEQ*TT
#define DD    514
#define HH    128
#define G4    512
#define KPAD  544     // 17*32, zero-padded K for split-B arrays

typedef _Float16 h2v __attribute__((ext_vector_type(2)));
typedef short bf16x8 __attribute__((ext_vector_type(8)));
typedef float f32x4 __attribute__((ext_vector_type(4)));

// ---------------- init helpers ----------------
__device__ __forceinline__ float winval(int k) {
  if (k < 96 || k >= 416) return 0.f;
  return 0.5f - 0.5f * cosf((float)(2.0 * M_PI / 320.0) * (float)(k - 96));
}

__device__ __forceinline__ void split_bf16(float v, unsigned short* h, unsigned short* l) {
  unsigned int hb = __float_as_uint(v) >> 16;
  float r = v - __uint_as_float(hb << 16);
  *h = (unsigned short)hb;
  *l = (unsigned short)(__float_as_uint(r) >> 16);
}

__global__ void k_wsq(float* __restrict__ wsq) {
  int p = blockIdx.x * 256 + threadIdx.x;
  if (p >= XPLEN) return;
  int t0 = (p <= 511) ? 0 : (p - 352) / 160;
  int t1 = p / 160; if (t1 > 600) t1 = 600;
  float s = 0.f;
  for (int t = t0; t <= t1; t++) { float w = winval(p - t * HOP); s += w * w; }
  wsq[p] = s;
}

// BF split: Bt[n][k] = DFT-forward[k][n]
__global__ void k_bfsplit(unsigned short* __restrict__ H, unsigned short* __restrict__ L) {
  int idx = blockIdx.x * 256 + threadIdx.x;
  if (idx >= 640 * KPAD) return;
  int n = idx / KPAD, k = idx - n * KPAD;
  float v = 0.f;
  if (n < DD && k < NFFT) {
    float w = winval(k);
    int f = (n < NF) ? n : n - NF;
    int m = (k * f) & 511;
    float th = (float)(M_PI / 256.0) * (float)m;
    v = ((n < NF) ? cosf(th) : -sinf(th)) * w;
  }
  split_bf16(v, &H[idx], &L[idx]);
}

// WT split: Bt[n][k] = Wih[n][k]
__global__ void k_wtsplit(const float* __restrict__ Wih, unsigned short* __restrict__ H,
                          unsigned short* __restrict__ L) {
  int idx = blockIdx.x * 256 + threadIdx.x;
  if (idx >= G4 * KPAD) return;
  int n = idx / KPAD, k = idx - n * KPAD;
  float v = (k < DD) ? Wih[n * DD + k] : 0.f;
  split_bf16(v, &H[idx], &L[idx]);
}

// BI split: Bt[n][kk] = BI[kk][n]
__global__ void k_bisplit(unsigned short* __restrict__ H, unsigned short* __restrict__ L) {
  int idx = blockIdx.x * 256 + threadIdx.x;
  if (idx >= NFFT * KPAD) return;
  int n = idx / KPAD, kk = idx - n * KPAD;
  float v = 0.f;
  if (kk < DD) {
    float w = winval(n);
    int f = (kk < NF) ? kk : kk - NF;
    int edge = (f == 0 || f == 256);
    float alpha = edge ? 1.f : 2.f;
    int m = (n * f) & 511;
    float th = (float)(M_PI / 256.0) * (float)m;
    float c;
    if (kk < NF) c = alpha * cosf(th);
    else         c = edge ? 0.f : -alpha * sinf(th);
    v = c * w * (1.f / 512.f);
  }
  split_bf16(v, &H[idx], &L[idx]);
}

__global__ void k_bsum(const float* __restrict__ bih, const float* __restrict__ bhh,
                       float* __restrict__ BSUM) {
  int idx = blockIdx.x * 256 + threadIdx.x;
  if (idx < G4) BSUM[idx] = bih[idx] + bhh[idx];
}

// W1/W2 mask-weight split: Ws[n'][k], n' = ri*320 + f (ri=0 real, 1 imag), k<128
__global__ void k_wmsplit(const float* __restrict__ W1, const float* __restrict__ W2,
                          unsigned short* __restrict__ W1h, unsigned short* __restrict__ W1l,
                          unsigned short* __restrict__ W2h, unsigned short* __restrict__ W2l) {
  int idx = blockIdx.x * 256 + threadIdx.x;
  if (idx >= 2 * 640 * HH) return;
  int m = idx / (640 * HH);
  int rem = idx - m * 640 * HH;
  int np = rem / HH, k = rem - np * HH;
  int ri = np / 320, f = np - ri * 320;
  float v = 0.f;
  if (f < NF) {
    int fcol = (ri == 0) ? f : NF + f;
    v = (m == 0) ? W1[fcol * HH + k] : W2[fcol * HH + k];
  }
  unsigned short h, l;
  split_bf16(v, &h, &l);
  if (m == 0) { W1h[rem] = h; W1l[rem] = l; }
  else        { W2h[rem] = h; W2l[rem] = l; }
}

// pack Whh into f16 pairs, uint4-transposed
__global__ void k_wpack(const float* __restrict__ Whh, unsigned int* __restrict__ WhhP4) {
  int idx = blockIdx.x * 256 + threadIdx.x;
  if (idx >= G4 * 64) return;
  int j = idx >> 6, k2 = idx & 63;
  _Float16 lo = (_Float16)Whh[j * HH + 2 * k2];
  _Float16 hi = (_Float16)Whh[j * HH + 2 * k2 + 1];
  unsigned int u = ((unsigned int)__builtin_bit_cast(unsigned short, hi) << 16)
                 |  (unsigned int)__builtin_bit_cast(unsigned short, lo);
  WhhP4[(k2 >> 2) * (G4 * 4) + j * 4 + (k2 & 3)] = u;
}

// reflect-padded multichannel extraction: XP[n][i], n=b*8+c
__global__ void k_xp(const float* __restrict__ x, float* __restrict__ XP) {
  int idx = blockIdx.x * 256 + threadIdx.x;
  if (idx >= NSEQ * XPLEN) return;
  int n = idx / XPLEN, i = idx - n * XPLEN;
  int j = i - FPAD;
  if (j < 0) j = -j;
  else if (j >= LSEQ) j = 2 * LSEQ - 2 - j;
  int b = n >> 3, c = n & 7;
  XP[idx] = x[((long)b * LSEQ + j) * NCH + c];
}

// ---------------- split-bf16 MFMA GEMM: C[M,N] = A[M,K] * Bt^T (+bias) ----------------
template <int GATHER>
__launch_bounds__(256)
__global__ void k_gemm3(const float* __restrict__ A,
                        const unsigned short* __restrict__ Bth,
                        const unsigned short* __restrict__ Btl,
                        const float* __restrict__ bias, float* __restrict__ C,
                        int M, int N, int K, int lda, int ldc) {
  __shared__ __align__(16) unsigned short sAh[128 * 40];
  __shared__ __align__(16) unsigned short sAl[128 * 40];
  __shared__ __align__(16) unsigned short sBh[128 * 40];
  __shared__ __align__(16) unsigned short sBl[128 * 40];
  const int tid = threadIdx.x;
  const int row0 = blockIdx.y * 128, col0 = blockIdx.x * 128;
  const int sar = tid >> 1, sak = (tid & 1) * 16;
  const int arow = row0 + sar;
  long abase;
  if (GATHER) { int nn = arow / TT; int t = arow - nn * TT; abase = (long)nn * XPLEN + (long)t * HOP; }
  else        { abase = (long)arow * lda; }
  const bool arok = (arow < M);
  const int lane = tid & 63, w = tid >> 6;
  const int wm = (w >> 1) * 64, wn = (w & 1) * 64;
  const int l15 = lane & 15, quad = lane >> 4;
  f32x4 acc[4][4] = {};
  unsigned int* aH = (unsigned int*)sAh;
  unsigned int* aL = (unsigned int*)sAl;
  uint4* bH = (uint4*)sBh;
  uint4* bL = (uint4*)sBl;
  for (int k0 = 0; k0 < K; k0 += 32) {
#pragma unroll
    for (int i = 0; i < 8; i++) {
      int kk = k0 + sak + 2 * i;
      float v0 = 0.f, v1 = 0.f;
      if (arok) {
        if (kk + 1 < K) { float2 t2 = *(const float2*)(A + abase + kk); v0 = t2.x; v1 = t2.y; }
        else if (kk < K) { v0 = A[abase + kk]; }
      }
      unsigned int h0 = __float_as_uint(v0) >> 16, h1 = __float_as_uint(v1) >> 16;
      float r0 = v0 - __uint_as_float(h0 << 16), r1 = v1 - __uint_as_float(h1 << 16);
      unsigned int l0 = __float_as_uint(r0) >> 16, l1 = __float_as_uint(r1) >> 16;
      aH[sar * 20 + (sak >> 1) + i] = h0 | (h1 << 16);
      aL[sar * 20 + (sak >> 1) + i] = l0 | (l1 << 16);
    }
#pragma unroll
    for (int h = 0; h < 2; h++) {
      int idx = tid + h * 256;
      int r = idx >> 2, c = idx & 3;
      long go = (long)(col0 + r) * KPAD + k0 + c * 8;
      bH[r * 5 + c] = *(const uint4*)(Bth + go);
      bL[r * 5 + c] = *(const uint4*)(Btl + go);
    }
    __syncthreads();
    bf16x8 ah[4], al[4], bh[4], bl[4];
#pragma unroll
    for (int i = 0; i < 4; i++) {
      int off = (wm + i * 16 + l15) * 40 + quad * 8;
      ah[i] = *(const bf16x8*)(sAh + off);
      al[i] = *(const bf16x8*)(sAl + off);
      int boff = (wn + i * 16 + l15) * 40 + quad * 8;
      bh[i] = *(const bf16x8*)(sBh + boff);
      bl[i] = *(const bf16x8*)(sBl + boff);
    }
#pragma unroll
    for (int i = 0; i < 4; i++)
#pragma unroll
      for (int j = 0; j < 4; j++) {
        acc[i][j] = __builtin_amdgcn_mfma_f32_16x16x32_bf16(al[i], bh[j], acc[i][j], 0, 0, 0);
        acc[i][j] = __builtin_amdgcn_mfma_f32_16x16x32_bf16(ah[i], bl[j], acc[i][j], 0, 0, 0);
        acc[i][j] = __builtin_amdgcn_mfma_f32_16x16x32_bf16(ah[i], bh[j], acc[i][j], 0, 0, 0);
      }
    __syncthreads();
  }
#pragma unroll
  for (int i = 0; i < 4; i++)
#pragma unroll
    for (int j = 0; j < 4; j++) {
      int cc = col0 + wn + j * 16 + l15;
      if (cc >= N) continue;
      float bv = bias ? bias[cc] : 0.f;
#pragma unroll
      for (int rg = 0; rg < 4; rg++) {
        int rr = row0 + wm + i * 16 + quad * 4 + rg;
        if (rr < M) C[(long)rr * ldc + cc] = acc[i][j][rg] + bv;
      }
    }
}

// ---------------- LSTM v8 (r10, plateau ~500us): coalesced refetch + dot2 ----------------
__device__ __forceinline__ float tanh_fast(float x) {
  float e = __expf(2.f * x);
  return 1.f - 2.f / (e + 1.f);
}

__launch_bounds__(512, 2)
__global__ void k_lstm(const float* __restrict__ XW, const unsigned int* __restrict__ WhhP4,
                       float* __restrict__ Hout) {
  __shared__ unsigned int hl2[64];   // h packed as 64 f16-pairs
  __shared__ float gl[G4];
  const int j = threadIdx.x;
  const int n = blockIdx.x;
  const uint4* W4 = (const uint4*)WhhP4;
  unsigned int wp[64];
#pragma unroll
  for (int i4 = 0; i4 < 16; i4++) {
    uint4 v = W4[i4 * G4 + j];
    wp[4 * i4]     = v.x;
    wp[4 * i4 + 1] = v.y;
    wp[4 * i4 + 2] = v.z;
    wp[4 * i4 + 3] = v.w;
  }
  float cst = 0.f;
  if (j < 64) hl2[j] = 0u;
  const float* xwrow = XW + (long)n * TT * G4 + j;
  const int lane = j & 63;
  float xnext = xwrow[0];
  __syncthreads();
  for (int t = 0; t < TT; t++) {
    float xv = xnext;
    if (t + 1 < TT) xnext = xwrow[(t + 1) * G4];
    unsigned int vh = hl2[lane];
    float a0 = 0.f, a1 = 0.f, a2 = 0.f, a3 = 0.f;
#pragma unroll
    for (int q = 0; q < 16; q++) {
      unsigned int p0 = __builtin_amdgcn_readlane(vh, 4 * q);
      unsigned int p1 = __builtin_amdgcn_readlane(vh, 4 * q + 1);
      unsigned int p2 = __builtin_amdgcn_readlane(vh, 4 * q + 2);
      unsigned int p3 = __builtin_amdgcn_readlane(vh, 4 * q + 3);
      a0 = __builtin_amdgcn_fdot2(__builtin_bit_cast(h2v, p0), __builtin_bit_cast(h2v, wp[4 * q]),     a0, false);
      a1 = __builtin_amdgcn_fdot2(__builtin_bit_cast(h2v, p1), __builtin_bit_cast(h2v, wp[4 * q + 1]), a1, false);
      a2 = __builtin_amdgcn_fdot2(__builtin_bit_cast(h2v, p2), __builtin_bit_cast(h2v, wp[4 * q + 2]), a2, false);
      a3 = __builtin_amdgcn_fdot2(__builtin_bit_cast(h2v, p3), __builtin_bit_cast(h2v, wp[4 * q + 3]), a3, false);
    }
    gl[j] = ((a0 + a1) + (a2 + a3)) + xv;
    __syncthreads();
    if (j < HH) {
      float gi = gl[j], gf = gl[HH + j], gg = gl[2 * HH + j], go = gl[3 * HH + j];
      float si = 1.f / (1.f + __expf(-gi));
      float sf = 1.f / (1.f + __expf(-gf));
      float so = 1.f / (1.f + __expf(-go));
      cst = sf * cst + si * tanh_fast(gg);
      float hv = so * tanh_fast(cst);
      ((_Float16*)hl2)[j] = (_Float16)hv;
      Hout[((long)n * TT + t) * HH + j] = hv;
    }
    __syncthreads();
  }
}

// ---------------- mask GEMM v2 (split-bf16 MFMA) + mask apply + transpose ----------------
// Tile 64 rows x 64 cols (cols 0..31 = real f0+c, 32..63 = imag). K=128.
// GEMM numerics identical to k_gemm3's 3-term split (absmax-proven).
__launch_bounds__(256)
__global__ void k_maskms(const float* __restrict__ Hout,
                         const unsigned short* __restrict__ Wsh,
                         const unsigned short* __restrict__ Wsl,
                         const float* __restrict__ bias, const float* __restrict__ S,
                         float* __restrict__ MS) {
  __shared__ __align__(16) unsigned short sAh[64 * 40];
  __shared__ __align__(16) unsigned short sAl[64 * 40];
  __shared__ __align__(16) unsigned short sBh[64 * 40];
  __shared__ __align__(16) unsigned short sBl[64 * 40];
  __shared__ float Cs[64][68];
  __shared__ float SR[64][33];
  __shared__ float SI[64][33];
  const int tid = threadIdx.x;
  const int f0 = blockIdx.x * 32;
  const int row0 = blockIdx.y * 64;
  const int lane = tid & 63, w = tid >> 6;
  const int wm = w * 16;
  const int l15 = lane & 15, quad = lane >> 4;
  const int sar = tid >> 2;            // 0..63 row / col
  const int sak = (tid & 3) * 8;       // k offset 0,8,16,24
  const int np = ((sar < 32) ? 0 : 320 - 32) + f0 + sar;   // ri*320 + f
  unsigned int* aH = (unsigned int*)sAh;
  unsigned int* aL = (unsigned int*)sAl;
  f32x4 acc[4] = {};
  for (int k0 = 0; k0 < HH; k0 += 32) {
    // A: Hout[row0+sar][k0+sak..+7] fp32 -> hi/lo bf16
    {
      const float* ap = Hout + (long)(row0 + sar) * HH + k0 + sak;
      float4 v0 = *(const float4*)ap;
      float4 v1 = *(const float4*)(ap + 4);
      float vv[8] = {v0.x, v0.y, v0.z, v0.w, v1.x, v1.y, v1.z, v1.w};
#pragma unroll
      for (int i = 0; i < 4; i++) {
        unsigned int h0 = __float_as_uint(vv[2 * i]) >> 16, h1 = __float_as_uint(vv[2 * i + 1]) >> 16;
        float r0 = vv[2 * i] - __uint_as_float(h0 << 16), r1 = vv[2 * i + 1] - __uint_as_float(h1 << 16);
        unsigned int l0 = __float_as_uint(r0) >> 16, l1 = __float_as_uint(r1) >> 16;
        aH[sar * 20 + (sak >> 1) + i] = h0 | (h1 << 16);
        aL[sar * 20 + (sak >> 1) + i] = l0 | (l1 << 16);
      }
    }
    // B: pre-split Ws[n'][k] 16B copies
    {
      long go = (long)np * HH + k0 + sak;
      *(uint4*)(sBh + sar * 40 + sak) = *(const uint4*)(Wsh + go);
      *(uint4*)(sBl + sar * 40 + sak) = *(const uint4*)(Wsl + go);
    }
    __syncthreads();
    bf16x8 ah = *(const bf16x8*)(sAh + (wm + l15) * 40 + quad * 8);
    bf16x8 al = *(const bf16x8*)(sAl + (wm + l15) * 40 + quad * 8);
#pragma unroll
    for (int ct = 0; ct < 4; ct++) {
      bf16x8 bh = *(const bf16x8*)(sBh + (ct * 16 + l15) * 40 + quad * 8);
      bf16x8 bl = *(const bf16x8*)(sBl + (ct * 16 + l15) * 40 + quad * 8);
      acc[ct] = __builtin_amdgcn_mfma_f32_16x16x32_bf16(al, bh, acc[ct], 0, 0, 0);
      acc[ct] = __builtin_amdgcn_mfma_f32_16x16x32_bf16(ah, bl, acc[ct], 0, 0, 0);
      acc[ct] = __builtin_amdgcn_mfma_f32_16x16x32_bf16(ah, bh, acc[ct], 0, 0, 0);
    }
    __syncthreads();
  }
  // epilogue: C (col=l15 within tile, row=quad*4+rg) -> Cs with bias
#pragma unroll
  for (int ct = 0; ct < 4; ct++) {
    int col = ct * 16 + l15;
    int f = f0 + (col & 31);
    int fcol = (col < 32) ? f : NF + f;
    float bv = (f < NF) ? bias[fcol] : 0.f;
#pragma unroll
    for (int rg = 0; rg < 4; rg++) Cs[wm + quad * 4 + rg][col] = acc[ct][rg] + bv;
  }
  __syncthreads();
  // phase A: masked spec (coalesced over f)
  {
    int fl = tid & 31, r8 = tid >> 5;
    int f = f0 + fl;
#pragma unroll
    for (int i = 0; i < 8; i++) {
      int rl = r8 * 8 + i;
      int rr = row0 + rl;
      float rm = Cs[rl][fl], im = Cs[rl][32 + fl];
      float sr = 0.f, si = 0.f;
      if (f < NF) { sr = S[(long)rr * DD + f]; si = S[(long)rr * DD + NF + f]; }
      SR[rl][fl] = rm * sr - im * si;
      SI[rl][fl] = rm * si + im * sr;
    }
  }
  __syncthreads();
  // phase B: transposed write (coalesced over t)
  {
    int tl = tid & 63, fq = tid >> 6;
    int rr = row0 + tl;
    int n = rr / TT, t = rr - n * TT;
    int b = n >> 3, c = n & 7;
#pragma unroll
    for (int i = 0; i < 8; i++) {
      int fl = fq * 8 + i;
      int f = f0 + fl;
      if (f < NF) {
        long addr = ((((long)b * NF + f) * 8 + c) * 2) * TT + t;
        MS[addr] = SR[tl][fl];
        MS[addr + TT] = SI[tl][fl];
      }
    }
  }
}

// ---------------- PSD: one block per (b,f) ----------------
__launch_bounds__(256)
__global__ void k_psd(const float* __restrict__ MS, float* __restrict__ PSD) {
  __shared__ float buf[9616];
  __shared__ float part[64][8];
  const int tid = threadIdx.x;
  const long base = (long)blockIdx.x * 9616;
  for (int i = tid; i < 9616; i += 256) buf[i] = MS[base + i];
  __syncthreads();
  int p = tid & 63, q = tid >> 6;
  int c = p >> 3, e = p & 7;
  const float* xc = &buf[c * 1202];
  const float* xe = &buf[e * 1202];
  int t0 = q * 150, t1 = (q == 3) ? TT : t0 + 150;
  float ar = 0.f, ai = 0.f;
  for (int t = t0; t < t1; t++) {
    float cr = xc[t], ci = xc[TT + t];
    float er = xe[t], ei = xe[TT + t];
    ar += cr * er + ci * ei;
    ai += ci * er - cr * ei;
  }
  part[p][q * 2] = ar; part[p][q * 2 + 1] = ai;
  __syncthreads();
  if (tid < 64) {
    float sr = part[tid][0] + part[tid][2] + part[tid][4] + part[tid][6];
    float si = part[tid][1] + part[tid][3] + part[tid][5] + part[tid][7];
    PSD[((long)blockIdx.x * 64 + tid) * 2]     = sr * (1.f / 601.f);
    PSD[((long)blockIdx.x * 64 + tid) * 2 + 1] = si * (1.f / 601.f);
  }
}

// ---------------- 8x8 complex solve + MVDR weight ----------------
__launch_bounds__(64)
__global__ void k_solve(const float* __restrict__ PS, const float* __restrict__ PN,
                        float* __restrict__ WV) {
  int idx = blockIdx.x * 64 + threadIdx.x;
  if (idx >= NB * NF) return;
  float Ar[8][8], Ai[8][8], Br[8][8], Bi[8][8];
  const float* pn = PN + (long)idx * 128;
  const float* ps = PS + (long)idx * 128;
  for (int i = 0; i < 8; i++)
    for (int j = 0; j < 8; j++) {
      Ar[i][j] = pn[(i * 8 + j) * 2]; Ai[i][j] = pn[(i * 8 + j) * 2 + 1];
      Br[i][j] = ps[(i * 8 + j) * 2]; Bi[i][j] = ps[(i * 8 + j) * 2 + 1];
    }
  float tr = 0.f;
  for (int i = 0; i < 8; i++) tr += Ar[i][i];
  float load = 1e-6f * tr / 8.f + 1e-8f;
  for (int i = 0; i < 8; i++) Ar[i][i] += load;
  for (int k = 0; k < 8; k++) {
    int piv = k; float mx = Ar[k][k] * Ar[k][k] + Ai[k][k] * Ai[k][k];
    for (int i = k + 1; i < 8; i++) {
      float m2 = Ar[i][k] * Ar[i][k] + Ai[i][k] * Ai[i][k];
      if (m2 > mx) { mx = m2; piv = i; }
    }
    if (piv != k) {
      for (int j = 0; j < 8; j++) {
        float t0;
        t0 = Ar[k][j]; Ar[k][j] = Ar[piv][j]; Ar[piv][j] = t0;
        t0 = Ai[k][j]; Ai[k][j] = Ai[piv][j]; Ai[piv][j] = t0;
        t0 = Br[k][j]; Br[k][j] = Br[piv][j]; Br[piv][j] = t0;
        t0 = Bi[k][j]; Bi[k][j] = Bi[piv][j]; Bi[piv][j] = t0;
      }
    }
    float dr = Ar[k][k], di = Ai[k][k];
    float inv = 1.f / (dr * dr + di * di);
    float irr = dr * inv, iii = -di * inv;
    for (int j = 0; j < 8; j++) {
      float xr = Ar[k][j], xi = Ai[k][j];
      Ar[k][j] = xr * irr - xi * iii; Ai[k][j] = xr * iii + xi * irr;
      xr = Br[k][j]; xi = Bi[k][j];
      Br[k][j] = xr * irr - xi * iii; Bi[k][j] = xr * iii + xi * irr;
    }
    for (int i = 0; i < 8; i++) {
      if (i == k) continue;
      float fr = Ar[i][k], fi = Ai[i][k];
      for (int j = 0; j < 8; j++) {
        float kr = Ar[k][j], ki = Ai[k][j];
        Ar[i][j] -= fr * kr - fi * ki;
        Ai[i][j] -= fr * ki + fi * kr;
        kr = Br[k][j]; ki = Bi[k][j];
        Br[i][j] -= fr * kr - fi * ki;
        Bi[i][j] -= fr * ki + fi * kr;
      }
    }
  }
  float trr = 1e-8f, tri = 0.f;
  for (int i = 0; i < 8; i++) { trr += Br[i][i]; tri += Bi[i][i]; }
  float inv = 1.f / (trr * trr + tri * tri);
  for (int c = 0; c < 8; c++) {
    float xr = Br[c][0], xi = Bi[c][0];
    WV[((long)idx * 8 + c) * 2]     = (xr * trr + xi * tri) * inv;
    WV[((long)idx * 8 + c) * 2 + 1] = (xi * trr - xr * tri) * inv;
  }
}

// ---------------- beamform ----------------
__launch_bounds__(320)
__global__ void k_beam(const float* __restrict__ S, const float* __restrict__ WV,
                       float* __restrict__ ENH) {
  __shared__ float WL[NF * 16];
  int bb = blockIdx.x / TT, t = blockIdx.x - bb * TT;
  for (int i = threadIdx.x; i < NF * 16; i += 320) WL[i] = WV[(long)bb * NF * 16 + i];
  __syncthreads();
  int f = threadIdx.x;
  if (f >= NF) return;
  float er = 0.f, ei = 0.f;
#pragma unroll
  for (int c = 0; c < 8; c++) {
    float wr = WL[(f * 8 + c) * 2], wi = WL[(f * 8 + c) * 2 + 1];
    const float* srow = S + (((long)(bb * 8 + c) * TT) + t) * DD;
    float sr = srow[f], si = srow[NF + f];
    er += wr * sr + wi * si;
    ei += wr * si - wi * sr;
  }
  float* erow = ENH + ((long)bb * TT + t) * DD;
  erow[f] = er;
  erow[NF + f] = ei;
}

// ---------------- overlap-add + normalize + crop ----------------
__global__ void k_ola(const float* __restrict__ IFR, const float* __restrict__ WSQ,
                      float* __restrict__ out) {
  int idx = blockIdx.x * 256 + threadIdx.x;
  if (idx >= NB * LSEQ) return;
  int b = idx / LSEQ, l = idx - b * LSEQ;
  int p = l + FPAD;
  int t0 = (p <= 511) ? 0 : (p - 352) / 160;
  int t1 = p / 160; if (t1 > 600) t1 = 600;
  float s = 0.f;
  for (int t = t0; t <= t1; t++) s += IFR[((long)b * TT + t) * NFFT + (p - t * HOP)];
  out[idx] = s / fmaxf(WSQ[p], 1e-11f);
}

// ---------------- driver ----------------
extern "C" void kernel_launch(void* const* d_in, const int* in_sizes, int n_in,
                              void* d_out, int out_size, void* d_ws, size_t ws_size,
                              hipStream_t stream) {
  (void)in_sizes; (void)n_in; (void)out_size; (void)ws_size;
  const float* x   = (const float*)d_in[0];
  const float* Wih = (const float*)d_in[1];
  const float* Whh = (const float*)d_in[2];
  const float* bih = (const float*)d_in[3];
  const float* bhh = (const float*)d_in[4];
  const float* W1  = (const float*)d_in[5];
  const float* b1  = (const float*)d_in[6];
  const float* W2  = (const float*)d_in[7];
  const float* b2  = (const float*)d_in[8];
  float* ws = (float*)d_ws;

  float* XP    = ws + 0;          // 6,176,768 (later IFR)
  float* S     = ws + 6176768;    // 19,774,496
  float* XWM   = ws + 25951264;   // 19,774,496 (XW then MS; WhhP4 in tail)
  float* HOUT  = ws + 45725760;   // 4,924,288 (later ENH)
  float* PSD_S = ws + 50650048;   // 263,168
  float* PSD_N = ws + 50913216;   // 263,168
  float* WV    = ws + 51176384;   // 32,896
  float* BSUM  = ws + 51209280;   // 512
  float* WSQ   = ws + 51209792;   // 96,512 -> 51,306,304
  unsigned short* W1sh = (unsigned short*)(ws + 51306304); // 640*128 ush = 40,960 fl
  unsigned short* W1sl = (unsigned short*)(ws + 51347264);
  unsigned short* W2sh = (unsigned short*)(ws + 51388224);
  unsigned short* W2sl = (unsigned short*)(ws + 51429184); // -> 51,470,144
  unsigned short* BFth = (unsigned short*)(ws + 51470144); // 640*544 = 174,080 fl
  unsigned short* BFtl = (unsigned short*)(ws + 51644224);
  unsigned short* WTth = (unsigned short*)(ws + 51818304); // 512*544 = 139,264 fl
  unsigned short* WTtl = (unsigned short*)(ws + 51957568);
  unsigned short* BIth = (unsigned short*)(ws + 52096832);
  unsigned short* BItl = (unsigned short*)(ws + 52236096); // -> end 52,375,360 (~199.8MB)
  float* MS    = XWM;
  float* ENH   = HOUT;
  float* IFR   = XP;
  unsigned int* WhhP4 = (unsigned int*)(XWM + 19693568);   // after true end of XW

  k_wsq<<<(XPLEN + 255) / 256, 256, 0, stream>>>(WSQ);
  k_bfsplit<<<(640 * KPAD + 255) / 256, 256, 0, stream>>>(BFth, BFtl);
  k_wtsplit<<<(G4 * KPAD + 255) / 256, 256, 0, stream>>>(Wih, WTth, WTtl);
  k_bisplit<<<(NFFT * KPAD + 255) / 256, 256, 0, stream>>>(BIth, BItl);
  k_bsum<<<2, 256, 0, stream>>>(bih, bhh, BSUM);
  k_wmsplit<<<(2 * 640 * HH + 255) / 256, 256, 0, stream>>>(W1, W2, W1sh, W1sl, W2sh, W2sl);
  k_wpack<<<(G4 * 64 + 255) / 256, 256, 0, stream>>>(Whh, WhhP4);
  k_xp<<<(NSEQ * XPLEN + 255) / 256, 256, 0, stream>>>(x, XP);

  // STFT: S[38464,514] = frames(XP) @ BF
  {
    dim3 g(5, 301);
    k_gemm3<1><<<g, 256, 0, stream>>>(XP, BFth, BFtl, nullptr, S, NROWS, DD, NFFT, 0, DD);
  }
  // xW: XWM[38464,512] = S @ Wih^T + bsum
  {
    dim3 g(4, 301);
    k_gemm3<0><<<g, 256, 0, stream>>>(S, WTth, WTtl, BSUM, XWM, NROWS, G4, DD, DD, G4);
  }

  k_lstm<<<64, 512, 0, stream>>>(XWM, WhhP4, HOUT);

  dim3 gm(9, 601);
  k_maskms<<<gm, 256, 0, stream>>>(HOUT, W1sh, W1sl, b1, S, MS);
  k_psd<<<NB * NF, 256, 0, stream>>>(MS, PSD_S);
  k_maskms<<<gm, 256, 0, stream>>>(HOUT, W2sh, W2sl, b2, S, MS);
  k_psd<<<NB * NF, 256, 0, stream>>>(MS, PSD_N);

  k_solve<<<(NB * NF + 63) / 64, 64, 0, stream>>>(PSD_S, PSD_N, WV);
  k_beam<<<NB * TT, 320, 0, stream>>>(S, WV, ENH);

  // iSTFT: IFR[4808,512] = ENH @ BI
  {
    dim3 g(4, 38);
    k_gemm3<0><<<g, 256, 0, stream>>>(ENH, BIth, BItl, nullptr, IFR, NB * TT, NFFT, DD, DD, NFFT);
  }

  k_ola<<<(NB * LSEQ + 255) / 256, 256, 0, stream>>>(IFR, WSQ, (float*)d_out);
}